// Round 5
// baseline (472.377 us; speedup 1.0000x reference)
//
#include <hip/hip_runtime.h>

// PairDistanceLoss: loss_i = (sum_{y=1} exp(x)) * (sum_{y=0} exp(-x)) / (ni*(C-ni))
// output = mean_i loss_i (fp32 scalar). N=16384 rows, C=4096 cols.
//
// R4 post-mortem: nt loads (L1 bypass) 165->~136us kernel (~3.9 TB/s combined
// read; x 1.97 TB/s HBM + y 1.97 TB/s L3). Fill proves fabric does 6.7 TB/s
// one-way, so reads are allocation-capacity-limited, not DRAM-limited.
// R5: bypass L2 allocation too via asm `global_load_dwordx4 ... sc0 sc1 nt`
// (system-scope streaming; y still hits memory-side Infinity Cache). Manual
// software pipeline with fixed s_waitcnt vmcnt(N), waits tethered to the
// chunk's registers via "+v" so the compiler can't hoist uses above them.

typedef float    v4f __attribute__((ext_vector_type(4)));
typedef unsigned v4u __attribute__((ext_vector_type(4)));

#define C_DIM 4096
#define BLOCK 256
#define WPB   (BLOCK / 64)   // 4 waves per block
#define NBLK  4096           // 1 row per wave: 4096 blocks * 4 waves = 16384 rows

__global__ __launch_bounds__(BLOCK) void pdl_rows(const float* __restrict__ x,
                                                  const int* __restrict__ y,
                                                  float* __restrict__ partial) {
    const int lane = threadIdx.x & 63;
    const int wave = threadIdx.x >> 6;
    const int row  = blockIdx.x * WPB + wave;

    // per-lane base: lane l covers elements l*4 + k*256 (k = wave-load index)
    const v4f* xp = (const v4f*)(x + (size_t)row * C_DIM) + lane;
    const v4u* yp = (const v4u*)(y + (size_t)row * C_DIM) + lane;

    // 3 rotating chunk buffers; chunk = 2 x-loads + 2 y-loads (8 elems/lane)
    v4f xb0[2], xb1[2], xb2[2];
    v4u yb0[2], yb1[2], yb2[2];

    float pos = 0.0f, neg = 0.0f;
    int cnt = 0;

    auto issue = [&](v4f (&xb)[2], v4u (&yb)[2], int c) {
#pragma unroll
        for (int u = 0; u < 2; ++u) {
            const v4f* pa = xp + (c * 2 + u) * 64;
            const v4u* pb = yp + (c * 2 + u) * 64;
            asm volatile("global_load_dwordx4 %0, %1, off sc0 sc1 nt"
                         : "=v"(xb[u]) : "v"(pa));
            asm volatile("global_load_dwordx4 %0, %1, off sc0 sc1 nt"
                         : "=v"(yb[u]) : "v"(pb));
        }
    };
    // s_waitcnt tethered to the buffer being consumed: "+v" makes these regs
    // appear modified by the asm, so no use can be scheduled before the wait.
    auto wait8 = [&](v4f (&xb)[2], v4u (&yb)[2]) {
        asm volatile("s_waitcnt vmcnt(8)"
                     : "+v"(xb[0]), "+v"(xb[1]), "+v"(yb[0]), "+v"(yb[1]));
    };
    auto wait4 = [&](v4f (&xb)[2], v4u (&yb)[2]) {
        asm volatile("s_waitcnt vmcnt(4)"
                     : "+v"(xb[0]), "+v"(xb[1]), "+v"(yb[0]), "+v"(yb[1]));
    };
    auto wait0 = [&](v4f (&xb)[2], v4u (&yb)[2]) {
        asm volatile("s_waitcnt vmcnt(0)"
                     : "+v"(xb[0]), "+v"(xb[1]), "+v"(yb[0]), "+v"(yb[1]));
    };
    auto comp = [&](const v4f (&xb)[2], const v4u (&yb)[2]) {
#pragma unroll
        for (int u = 0; u < 2; ++u) {
#pragma unroll
            for (int e = 0; e < 4; ++e) {
                const unsigned yy = yb[u][e];
                const float    xx = xb[u][e];
                const float    ex = __expf(yy ? xx : -xx);
                pos += yy ? ex : 0.0f;
                neg += yy ? 0.0f : ex;
                cnt += (int)yy;
            }
        }
    };

    // 8 chunks per row; 3-deep pipeline, 12 loads in flight steady-state.
    issue(xb0, yb0, 0);
    issue(xb1, yb1, 1);
    issue(xb2, yb2, 2);
    wait8(xb0, yb0); comp(xb0, yb0); issue(xb0, yb0, 3);
    wait8(xb1, yb1); comp(xb1, yb1); issue(xb1, yb1, 4);
    wait8(xb2, yb2); comp(xb2, yb2); issue(xb2, yb2, 5);
    wait8(xb0, yb0); comp(xb0, yb0); issue(xb0, yb0, 6);
    wait8(xb1, yb1); comp(xb1, yb1); issue(xb1, yb1, 7);
    wait8(xb2, yb2); comp(xb2, yb2);
    wait4(xb0, yb0); comp(xb0, yb0);
    wait0(xb1, yb1); comp(xb1, yb1);

    // wave-64 reduction: lane 0 ends with the row totals
#pragma unroll
    for (int off = 32; off >= 1; off >>= 1) {
        pos += __shfl_down(pos, off, 64);
        neg += __shfl_down(neg, off, 64);
        cnt += __shfl_down(cnt, off, 64);
    }

    __shared__ float sacc[WPB];
    if (lane == 0) {
        const float denom = (float)cnt * (float)(C_DIM - cnt);
        sacc[wave] = (pos * neg) / denom;
    }
    __syncthreads();
    if (threadIdx.x == 0) {
        float b = 0.0f;
#pragma unroll
        for (int w = 0; w < WPB; ++w) b += sacc[w];
        partial[blockIdx.x] = b;
    }
}

__global__ __launch_bounds__(BLOCK) void pdl_reduce(const float* __restrict__ partial,
                                                    float* __restrict__ out,
                                                    int n_partial, float inv_n) {
    const float4* p4 = (const float4*)partial;
    float s = 0.0f;
    for (int i = threadIdx.x; i < n_partial / 4; i += BLOCK) {
        const float4 v = p4[i];
        s += (v.x + v.y) + (v.z + v.w);
    }
#pragma unroll
    for (int off = 32; off >= 1; off >>= 1) s += __shfl_down(s, off, 64);
    __shared__ float sw[BLOCK / 64];
    const int lane = threadIdx.x & 63;
    const int wave = threadIdx.x >> 6;
    if (lane == 0) sw[wave] = s;
    __syncthreads();
    if (threadIdx.x == 0) {
        float t = 0.0f;
#pragma unroll
        for (int w = 0; w < BLOCK / 64; ++w) t += sw[w];
        out[0] = t * inv_n;
    }
}

extern "C" void kernel_launch(void* const* d_in, const int* in_sizes, int n_in,
                              void* d_out, int out_size, void* d_ws, size_t ws_size,
                              hipStream_t stream) {
    const float* x = (const float*)d_in[0];
    const int*   y = (const int*)d_in[1];
    float* out = (float*)d_out;
    float* partial = (float*)d_ws;  // NBLK floats, fully rewritten each call

    const int n_rows = in_sizes[0] / C_DIM;  // 16384

    pdl_rows<<<NBLK, BLOCK, 0, stream>>>(x, y, partial);
    pdl_reduce<<<1, BLOCK, 0, stream>>>(partial, out, NBLK, 1.0f / (float)n_rows);
}